// Round 8
// baseline (98.892 us; speedup 1.0000x reference)
//
#include <hip/hip_runtime.h>

// SkipGram negative-sampling loss on MI355X — round 8.
// Depth lives in LDS, not VGPRs: global_load_lds (async global->LDS,
// 0 VGPRs/slot) with counted vmcnt waits. NBUF=7 ring, DEPTH=6 chunks
// (12 vmcnt ticks) in flight per wave. Wave-private LDS regions, no
// barriers in the K-loop. lgkmcnt(0) after ds_read makes slot reuse safe.

#define VOCAB  100000
#define EMB    128
#define B_TOT  16384
#define W_POS  10
#define K_NEG  64
#define N_LAB  (W_POS + K_NEG)   // 74
#define NCHUNK 19                // ceil(74/4)
#define DEPTH  6                 // chunks in flight (2 vmcnt ticks each)
#define NBUF   7                 // ring slots (DEPTH+1: no WAR on refill)

__device__ __forceinline__ float logsig(float x) {
    // log_sigmoid(x) = min(x,0) - log1p(exp(-|x|)); hw exp/log only.
    const float e = __expf(-fabsf(x));
    return fminf(x, 0.0f) - 0.69314718056f * __log2f(1.0f + e);
}

__device__ __forceinline__ void gload_lds16(const float* g, float* l) {
    // async 16B/lane global->LDS; LDS dest = uniform base + lane*16.
    __builtin_amdgcn_global_load_lds(
        (const __attribute__((address_space(1))) unsigned int*)g,
        (__attribute__((address_space(3))) unsigned int*)l,
        16, 0, 0);
}

__global__ __launch_bounds__(256) void skipgram_kernel(
    const int*   __restrict__ input,       // [B]
    const int*   __restrict__ pos_labels,  // [B, W_POS]
    const int*   __restrict__ neg_labels,  // [B, K_NEG]
    const float* __restrict__ input_emb,   // [VOCAB, EMB]
    const float* __restrict__ output_emb,  // [VOCAB, EMB]
    float*       __restrict__ out)         // [1]
{
    // Per-wave private staging: 4 waves x NBUF slots x 2 halves x 1KB.
    __shared__ __align__(16) float buf[4][NBUF][2][256];   // 28 KB

    const int lane = threadIdx.x & 63;
    const int gl   = lane & 15;   // lane within 16-lane group
    const int grp  = lane >> 4;   // which label of each 4-label chunk
    const int w    = threadIdx.x >> 6;   // wave id within block
    const int wave = (int)((blockIdx.x * blockDim.x + threadIdx.x) >> 6);
    const int b    = wave;        // one element per wave

    const int* pl = pos_labels + b * W_POS;
    const int* nl = neg_labels + b * K_NEG;

    // ---- all 19 index loads up front (independent, in flight) ----
    int idx[NCHUNK];
    #pragma unroll
    for (int t = 0; t < NCHUNK; ++t) {
        const int j = 4 * t + grp;
        idx[t] = (j < W_POS) ? pl[j] : ((j < N_LAB) ? nl[j - W_POS] : 0);
    }

    // ---- center row (registers) ----
    const int c = input[b];
    const float4* crow = (const float4*)(input_emb + (size_t)c * EMB);
    const float4 c0 = crow[gl * 2], c1 = crow[gl * 2 + 1];

    float acc = 0.0f;

    // Issue chunk t's two 1KB wave-loads into ring slot t%NBUF.
    // lane l = (grp,gl): row idx[t] of its group, bytes [gl*32+h*16).
#define ISSUE(t) do {                                                        \
        if ((t) < NCHUNK) {                                                  \
            const float* g0 = output_emb + (size_t)idx[(t)] * EMB + gl * 8;  \
            gload_lds16(g0,     &buf[w][(t) % NBUF][0][0]);                  \
            gload_lds16(g0 + 4, &buf[w][(t) % NBUF][1][0]);                  \
        }                                                                    \
    } while (0)

#define STEP(t, vm) do {                                                     \
        asm volatile("s_waitcnt vmcnt(" #vm ")" ::: "memory");               \
        __builtin_amdgcn_sched_barrier(0);                                   \
        const float4 a0 = *(const float4*)&buf[w][(t) % NBUF][0][lane * 4];  \
        const float4 a1 = *(const float4*)&buf[w][(t) % NBUF][1][lane * 4];  \
        asm volatile("s_waitcnt lgkmcnt(0)" ::: "memory");                   \
        __builtin_amdgcn_sched_barrier(0);                                   \
        ISSUE((t) + DEPTH);                                                  \
        float p = a0.x * c0.x + a0.y * c0.y + a0.z * c0.z + a0.w * c0.w      \
                + a1.x * c1.x + a1.y * c1.y + a1.z * c1.z + a1.w * c1.w;     \
        p += __shfl_xor(p, 1);                                               \
        p += __shfl_xor(p, 2);                                               \
        p += __shfl_xor(p, 4);                                               \
        p += __shfl_xor(p, 8);                                               \
        const int j = 4 * (t) + grp;                                         \
        if (gl == 0 && j < N_LAB) acc += logsig(p);                          \
    } while (0)

    // Prologue: fill DEPTH=6 slots (12 vmcnt ticks).
    ISSUE(0); ISSUE(1); ISSUE(2); ISSUE(3); ISSUE(4); ISSUE(5);

    // Steady state: chunk t complete when <=12 ticks outstanding
    // (refill for t+6 issued inside STEP after the reads).
    STEP(0, 12);  STEP(1, 12);  STEP(2, 12);  STEP(3, 12);
    STEP(4, 12);  STEP(5, 12);  STEP(6, 12);  STEP(7, 12);
    STEP(8, 12);  STEP(9, 12);  STEP(10, 12); STEP(11, 12);
    STEP(12, 12);
    // Tail: drain (no refills past chunk 18).
    STEP(13, 10); STEP(14, 8);  STEP(15, 6);  STEP(16, 4);
    STEP(17, 2);  STEP(18, 0);

#undef STEP
#undef ISSUE

    // ---- wave reduce (group leaders) then block reduce -> 1 atomic ----
    acc += __shfl_xor(acc, 16);
    acc += __shfl_xor(acc, 32);

    __shared__ float part[4];
    if (lane == 0) part[w] = acc;
    __syncthreads();
    if (threadIdx.x == 0) {
        const float s = part[0] + part[1] + part[2] + part[3];
        atomicAdd(out, -s);
    }
}

extern "C" void kernel_launch(void* const* d_in, const int* in_sizes, int n_in,
                              void* d_out, int out_size, void* d_ws, size_t ws_size,
                              hipStream_t stream) {
    const int*   input      = (const int*)  d_in[0];
    const int*   pos_labels = (const int*)  d_in[1];
    const int*   neg_labels = (const int*)  d_in[2];
    const float* input_emb  = (const float*)d_in[3];
    const float* output_emb = (const float*)d_in[4];
    float*       out        = (float*)      d_out;

    // d_out is poisoned (0xAA) and not re-zeroed between replays.
    hipMemsetAsync(out, 0, sizeof(float), stream);

    // 4096 blocks x 256 threads = 16384 waves -> 1 element per wave.
    dim3 grid(4096), block(256);
    hipLaunchKernelGGL(skipgram_kernel, grid, block, 0, stream,
                       input, pos_labels, neg_labels, input_emb, output_emb, out);
}